// Round 7
// baseline (55.997 us; speedup 1.0000x reference)
//
#include <hip/hip_runtime.h>
#include <hip/hip_bf16.h>

// SINDy: theta(N,969) @ (C*mask)(969,16), plus l1 = mean|C*mask|.
// N=262144, latent=16, lib = 1 + 16 + 136 + 816 = 969; K padded to 992 = 31*32.
//
// R5 design — no LDS-A: rotation i -> i+4 (mod 16) on latent indices makes the
// library rotation-closed; lane l (slice g=l>>4) computes the g-th orbit
// member of each of 248 orbit reps as compile-time-indexed products of its
// ROTATED z. Coefficients are gathered to match by the prep kernel.
// Each wave = one 16x16 out tile, 31 MFMAs.
//
// R7 change: stage the 31.75 KB B-table in LDS once per block. R2/R5/R6 all
// pinned at ~47 us across very different VALU loads -> latency-bound on the
// 31 per-chunk global B loads (table thrashes out of 32 KB L1 as z streams).
// ds_read_b128 at base + lane*16 + c*1024 is linear and conflict-free.

#define LIB    969
#define NSLOT  248
#define NCHUNK 31
#define NROWS  262144
#define NOUT   16
#define BTAB_U4 1984   // 31744 B / 16

typedef __attribute__((ext_vector_type(8))) short bf16x8;
typedef __attribute__((ext_vector_type(4))) float f32x4;

struct Maps {
  unsigned char a[NSLOT], b[NSLOT], c[NSLOT];  // zrot indices (16 = sentinel 1.0)
  short l[NSLOT][4];                           // library row per slice g, or -1
};

constexpr Maps build_maps() {
  Maps M{};
  int n = 0;
  // const term: product 1 in every slice; coeff only at g=0
  M.a[n] = 16; M.b[n] = 16; M.c[n] = 16;
  M.l[n][0] = 0; M.l[n][1] = -1; M.l[n][2] = -1; M.l[n][3] = -1; n++;
  // linear orbits: reps a0 = 0..3, member g = z_{(a0+4g)&15}
  for (int a0 = 0; a0 < 4; a0++) {
    M.a[n] = (unsigned char)a0; M.b[n] = 16; M.c[n] = 16;
    for (int g = 0; g < 4; g++) M.l[n][g] = (short)(1 + ((a0 + 4 * g) & 15));
    n++;
  }
  // pair orbits
  bool pv[16][16] = {};
  for (int i = 0; i < 16; i++)
    for (int j = i; j < 16; j++) {
      if (pv[i][j]) continue;
      M.a[n] = (unsigned char)i; M.b[n] = (unsigned char)j; M.c[n] = 16;
      int mi[4], mj[4];
      for (int g = 0; g < 4; g++) {
        int x = (i + 4 * g) & 15, y = (j + 4 * g) & 15;
        int lo = x < y ? x : y, hi = x < y ? y : x;
        mi[g] = lo; mj[g] = hi; pv[lo][hi] = true;
      }
      for (int g = 0; g < 4; g++) {
        bool dup = false;
        for (int h = 0; h < g; h++) if (mi[h] == mi[g] && mj[h] == mj[g]) dup = true;
        M.l[n][g] = dup ? (short)-1
                        : (short)(17 + mi[g] * 16 - mi[g] * (mi[g] - 1) / 2 + (mj[g] - mi[g]));
      }
      n++;
    }
  // triple orbits (all size 4)
  bool tv[16][16][16] = {};
  for (int i = 0; i < 16; i++)
    for (int j = i; j < 16; j++)
      for (int k = j; k < 16; k++) {
        if (tv[i][j][k]) continue;
        M.a[n] = (unsigned char)i; M.b[n] = (unsigned char)j; M.c[n] = (unsigned char)k;
        int ti[4], tj[4], tk[4];
        for (int g = 0; g < 4; g++) {
          int x = (i + 4 * g) & 15, y = (j + 4 * g) & 15, w = (k + 4 * g) & 15, t;
          if (x > y) { t = x; x = y; y = t; }
          if (y > w) { t = y; y = w; w = t; }
          if (x > y) { t = x; x = y; y = t; }
          ti[g] = x; tj[g] = y; tk[g] = w; tv[x][y][w] = true;
        }
        for (int g = 0; g < 4; g++) {
          bool dup = false;
          for (int h = 0; h < g; h++)
            if (ti[h] == ti[g] && tj[h] == tj[g] && tk[h] == tk[g]) dup = true;
          if (dup) { M.l[n][g] = -1; continue; }
          int i2 = ti[g], j2 = tj[g], k2 = tk[g];
          int base = 0;
          for (int a2 = 0; a2 < i2; a2++) base += (16 - a2) * (17 - a2) / 2;
          int off = (j2 - i2) * (16 - i2) - (j2 - i2) * (j2 - i2 - 1) / 2 + (k2 - j2);
          M.l[n][g] = (short)(153 + base + off);
        }
        n++;
      }
  // pad to 248 slots (product 1, coeff 0 everywhere)
  for (; n < NSLOT; n++) {
    M.a[n] = 16; M.b[n] = 16; M.c[n] = 16;
    M.l[n][0] = M.l[n][1] = M.l[n][2] = M.l[n][3] = -1;
  }
  return M;
}
constexpr Maps MP = build_maps();

// ---- prep: gather masked coeffs (bf16 RNE) into B-frag/slot order; L1 sum ----
__device__ inline unsigned short f2bf(float x) {
  unsigned int u = __builtin_bit_cast(unsigned int, x);
  u += 0x7fffu + ((u >> 16) & 1u);
  return (unsigned short)(u >> 16);
}
__global__ __launch_bounds__(256) void prep_kernel(const float* __restrict__ C,
                                                   const float* __restrict__ M,
                                                   unsigned short* __restrict__ Cb,
                                                   float* __restrict__ acc) {
  const int idx = blockIdx.x * 256 + threadIdx.x;   // 0 .. 15871 = NSLOT*4*16
  const int s = idx >> 6, g = (idx >> 4) & 3, o = idx & 15;
  const int li = MP.l[s][g];
  float v = 0.f;
  if (li >= 0) v = C[li * 16 + o] * M[li * 16 + o];
  Cb[(((s >> 3) * 4 + g) * 16 + o) * 8 + (s & 7)] = f2bf(v);
  float t = fabsf(v);
  #pragma unroll
  for (int off = 32; off > 0; off >>= 1) t += __shfl_down(t, off);
  if ((threadIdx.x & 63) == 0) atomicAdd(acc, t);
}

__global__ __launch_bounds__(256) void sindy_kernel(const float* __restrict__ z,
                                                    const unsigned short* __restrict__ Cb,
                                                    const float* __restrict__ acc,
                                                    float* __restrict__ out) {
  __shared__ uint4 Blds[BTAB_U4];                   // 31744 B coeff table
  const int lane = threadIdx.x & 63;
  const int g = lane >> 4;                          // k-slice
  const int o = lane & 15;                          // row-in-tile (A) / out col (B)
  const int rowBase = blockIdx.x * 64 + (threadIdx.x >> 6) * 16;
  const int r = rowBase + o;

  // load z-row r first (latency overlaps the LDS fill)
  float z17[17];
  {
    const float4* z4 = (const float4*)z;
    #pragma unroll
    for (int c4 = 0; c4 < 4; c4++) {
      float4 v = z4[r * 4 + c4];
      z17[c4 * 4 + 0] = v.x; z17[c4 * 4 + 1] = v.y;
      z17[c4 * 4 + 2] = v.z; z17[c4 * 4 + 3] = v.w;
    }
    z17[16] = 1.0f;
  }

  // cooperative one-time fill of the B-table (1984 uint4 / 256 threads)
  {
    const uint4* src = (const uint4*)Cb;
    #pragma unroll
    for (int i = 0; i < 8; i++) {
      int e = i * 256 + threadIdx.x;
      if (e < BTAB_U4) Blds[e] = src[e];
    }
  }
  __syncthreads();

  // rotate by 4g with two compile-time-indexed cndmask layers
  const bool b0 = (g & 1) != 0, b1 = (g & 2) != 0;
  float t16[16], zr[17];
  #pragma unroll
  for (int m = 0; m < 16; m++) t16[m] = b0 ? z17[(m + 4) & 15] : z17[m];
  #pragma unroll
  for (int m = 0; m < 16; m++) zr[m] = b1 ? t16[(m + 8) & 15] : t16[m];
  zr[16] = 1.0f;

  const char* bbase = (const char*)Blds + lane * 16;  // + c*1024 per chunk (imm)

  f32x4 acc4 = {0.f, 0.f, 0.f, 0.f};
  #pragma unroll
  for (int c = 0; c < NCHUNK; c++) {
    bf16x8 af;
    #pragma unroll
    for (int m = 0; m < 8; m++) {
      const int s = c * 8 + m;
      float th = (zr[MP.a[s]] * zr[MP.b[s]]) * zr[MP.c[s]];
      __hip_bfloat16 h = __float2bfloat16(th);       // compiler fuses to cvt_pk
      unsigned short u; __builtin_memcpy(&u, &h, 2);
      af[m] = (short)u;
    }
    bf16x8 bfrag = *(const bf16x8*)(bbase + c * 1024);  // ds_read_b128, conflict-free
    acc4 = __builtin_amdgcn_mfma_f32_16x16x32_bf16(af, bfrag, acc4, 0, 0, 0);
  }

  // C/D layout (m89-verified): col = lane&15, row = 4*(lane>>4) + reg
  #pragma unroll
  for (int p = 0; p < 4; p++)
    out[(rowBase + 4 * g + p) * 16 + o] = acc4[p];

  if (blockIdx.x == 0 && threadIdx.x == 0)
    out[NROWS * NOUT] = acc[0] * (1.0f / 15504.0f);  // mean over 969*16
}

extern "C" void kernel_launch(void* const* d_in, const int* in_sizes, int n_in,
                              void* d_out, int out_size, void* d_ws, size_t ws_size,
                              hipStream_t stream) {
  const float* z = (const float*)d_in[0];
  const float* C = (const float*)d_in[1];
  const float* M = (const float*)d_in[2];
  float* out = (float*)d_out;
  float* acc = (float*)d_ws;                          // [0]: L1 accumulator
  unsigned short* Cb = (unsigned short*)((char*)d_ws + 64); // 31744 B coeff slots

  (void)hipMemsetAsync(d_ws, 0, 4, stream);           // zero L1 accumulator
  prep_kernel<<<NSLOT * 4 * 16 / 256, 256, 0, stream>>>(C, M, Cb, acc);
  sindy_kernel<<<NROWS / 64, 256, 0, stream>>>(z, Cb, acc, out);
}